// Round 10
// baseline (291.196 us; speedup 1.0000x reference)
//
#include <hip/hip_runtime.h>

#define N_NODES 50000
#define SCAN_BLK 256
#define NBLK ((N_NODES + SCAN_BLK - 1) / SCAN_BLK)   // 196

// ---- CSR build ----
__global__ void cnt_kernel(const int* __restrict__ dst, int E, int* __restrict__ cnt) {
    int e = blockIdx.x * blockDim.x + threadIdx.x;
    if (e < E) atomicAdd(&cnt[dst[e]], 1);
}

__global__ void bsum_kernel(const int* __restrict__ cnt, int* __restrict__ bsum, int n) {
    __shared__ int sh[SCAN_BLK];
    int i = blockIdx.x * SCAN_BLK + threadIdx.x;
    sh[threadIdx.x] = (i < n) ? cnt[i] : 0;
    __syncthreads();
    for (int off = SCAN_BLK / 2; off > 0; off >>= 1) {
        if (threadIdx.x < off) sh[threadIdx.x] += sh[threadIdx.x + off];
        __syncthreads();
    }
    if (threadIdx.x == 0) bsum[blockIdx.x] = sh[0];
}

__global__ void bscan_kernel(const int* __restrict__ bsum, int* __restrict__ bbase, int nblk) {
    __shared__ int sh[SCAN_BLK];
    int tid = threadIdx.x;
    int v = (tid < nblk) ? bsum[tid] : 0;
    sh[tid] = v;
    __syncthreads();
    for (int off = 1; off < SCAN_BLK; off <<= 1) {
        int t = (tid >= off) ? sh[tid - off] : 0;
        __syncthreads();
        sh[tid] += t;
        __syncthreads();
    }
    if (tid < nblk) bbase[tid] = sh[tid] - v;   // exclusive
}

// per-block exclusive scan + rowptr/cursor emit + dis = rsqrt(cnt+1)
__global__ void scatter_scan_kernel(const int* __restrict__ cnt, const int* __restrict__ bbase,
                                    int* __restrict__ rowptr, int* __restrict__ cursor,
                                    float* __restrict__ dis, int n) {
    __shared__ int sh[SCAN_BLK];
    int tid = threadIdx.x;
    int i = blockIdx.x * SCAN_BLK + tid;
    int v = (i < n) ? cnt[i] : 0;
    sh[tid] = v;
    __syncthreads();
    for (int off = 1; off < SCAN_BLK; off <<= 1) {
        int t = (tid >= off) ? sh[tid - off] : 0;
        __syncthreads();
        sh[tid] += t;
        __syncthreads();
    }
    int excl = bbase[blockIdx.x] + sh[tid] - v;
    if (i < n) {
        rowptr[i] = excl;
        cursor[i] = excl;
        dis[i] = rsqrtf((float)v + 1.0f);
        if (i == n - 1) rowptr[n] = excl + v;
    }
}

__global__ void fill_kernel(const int* __restrict__ src, const int* __restrict__ dst,
                            int E, int* __restrict__ cursor, int* __restrict__ col) {
    int e = blockIdx.x * blockDim.x + threadIdx.x;
    if (e < E) {
        int pos = atomicAdd(&cursor[dst[e]], 1);
        col[pos] = src[e];
    }
}

// ---- vectorized wave-level CSR aggregation ----
// lane = (es = lane>>4 edge slot, q = lane&15 feature quad).
// 4 edges per load instr, float4 per lane, no shfl in inner loop.
// Returns self + sum of in-neighbor rows for quad q (all lanes hold the result).
__device__ __forceinline__ float4 agg_row_vec(const float* __restrict__ A,
        const int* __restrict__ rowptr, const int* __restrict__ col,
        int d, int es, int q) {
    const int beg = rowptr[d], deg = rowptr[d + 1] - beg;
    float4 acc = make_float4(0.f, 0.f, 0.f, 0.f);
    for (int base = 0; base < deg; base += 8) {
        int i0 = base + es, i1 = base + 4 + es;
        if (i0 < deg) {
            int s = col[beg + i0];
            float4 v = *reinterpret_cast<const float4*>(&A[(size_t)s * 64 + q * 4]);
            acc.x += v.x; acc.y += v.y; acc.z += v.z; acc.w += v.w;
        }
        if (i1 < deg) {
            int s = col[beg + i1];
            float4 v = *reinterpret_cast<const float4*>(&A[(size_t)s * 64 + q * 4]);
            acc.x += v.x; acc.y += v.y; acc.z += v.z; acc.w += v.w;
        }
    }
    // reduce the 4 edge slots: lanes ^16, ^32
    acc.x += __shfl_xor(acc.x, 16); acc.y += __shfl_xor(acc.y, 16);
    acc.z += __shfl_xor(acc.z, 16); acc.w += __shfl_xor(acc.w, 16);
    acc.x += __shfl_xor(acc.x, 32); acc.y += __shfl_xor(acc.y, 32);
    acc.z += __shfl_xor(acc.z, 32); acc.w += __shfl_xor(acc.w, 32);
    // self-loop (uniform across lanes)
    float4 sv = *reinterpret_cast<const float4*>(&A[(size_t)d * 64 + q * 4]);
    acc.x += sv.x; acc.y += sv.y; acc.z += sv.z; acc.w += sv.w;
    return acc;
}

// ---- standalone register-blocked MM (layer 1): Y = dis[row] * (X[n,K] @ W[K,64]) ----
template<int K>
__global__ __launch_bounds__(256) void mm_tiled(const float* __restrict__ X,
        const float* __restrict__ W, const float* __restrict__ dis,
        float* __restrict__ Y, int n) {
    constexpr int KC = 64;
    __shared__ float xs[32][KC + 1];
    const int tid = threadIdx.x;
    const int j4 = tid & 15;
    const int rp = tid >> 4;
    const int row0 = blockIdx.x * 32;
    const int col0 = j4 * 4;
    float acc[2][4] = {};

    for (int kc = 0; kc < K; kc += KC) {
        __syncthreads();
        #pragma unroll
        for (int it = 0; it < 2; ++it) {
            int idx = it * 256 + tid;
            int r = idx >> 4, c4 = idx & 15;
            int row = row0 + r;
            float4 v = make_float4(0.f, 0.f, 0.f, 0.f);
            if (row < n) v = *reinterpret_cast<const float4*>(&X[(size_t)row * K + kc + c4 * 4]);
            xs[r][c4 * 4 + 0] = v.x; xs[r][c4 * 4 + 1] = v.y;
            xs[r][c4 * 4 + 2] = v.z; xs[r][c4 * 4 + 3] = v.w;
        }
        __syncthreads();
        #pragma unroll 16
        for (int k = 0; k < KC; ++k) {
            const float4 w = *reinterpret_cast<const float4*>(&W[(size_t)(kc + k) * 64 + col0]);
            const float x0 = xs[rp * 2 + 0][k];
            const float x1 = xs[rp * 2 + 1][k];
            acc[0][0] = fmaf(x0, w.x, acc[0][0]);
            acc[0][1] = fmaf(x0, w.y, acc[0][1]);
            acc[0][2] = fmaf(x0, w.z, acc[0][2]);
            acc[0][3] = fmaf(x0, w.w, acc[0][3]);
            acc[1][0] = fmaf(x1, w.x, acc[1][0]);
            acc[1][1] = fmaf(x1, w.y, acc[1][1]);
            acc[1][2] = fmaf(x1, w.z, acc[1][2]);
            acc[1][3] = fmaf(x1, w.w, acc[1][3]);
        }
    }
    #pragma unroll
    for (int r = 0; r < 2; ++r) {
        int row = row0 + rp * 2 + r;
        if (row < n) {
            float s = dis[row];
            *reinterpret_cast<float4*>(&Y[(size_t)row * 64 + col0]) =
                make_float4(acc[r][0] * s, acc[r][1] * s, acc[r][2] * s, acc[r][3] * s);
        }
    }
}

// ---- fused agg + MM: xs(LDS) = relu(dis*(agg(A)+self)+bagg); Y = dis[row]*(xs @ W)
__global__ __launch_bounds__(256) void agg_mm_kernel(const float* __restrict__ A,
        const int* __restrict__ rowptr, const int* __restrict__ col,
        const float* __restrict__ dis, const float* __restrict__ bagg,
        const float* __restrict__ W, float* __restrict__ Y, int n) {
    __shared__ float xs[32][68];     // stride 68: 16B-aligned rows, conflict-free MM reads
    __shared__ float dl[32];
    const int tid = threadIdx.x;
    const int w = tid >> 6, lane = tid & 63;
    const int es = lane >> 4, q = lane & 15;
    const int row0 = blockIdx.x * 32;
    const float4 bv4 = *reinterpret_cast<const float4*>(&bagg[q * 4]);

    #pragma unroll
    for (int rr = 0; rr < 8; ++rr) {
        int lr = w * 8 + rr;
        int d = row0 + lr;
        if (d < n) {
            float4 acc = agg_row_vec(A, rowptr, col, d, es, q);
            float dd = dis[d];
            if (lane < 16) {
                float4 o;
                o.x = fmaxf(dd * acc.x + bv4.x, 0.0f);
                o.y = fmaxf(dd * acc.y + bv4.y, 0.0f);
                o.z = fmaxf(dd * acc.z + bv4.z, 0.0f);
                o.w = fmaxf(dd * acc.w + bv4.w, 0.0f);
                *reinterpret_cast<float4*>(&xs[lr][q * 4]) = o;
            }
            if (lane == 0) dl[lr] = dd;
        } else {
            if (lane < 16)
                *reinterpret_cast<float4*>(&xs[lr][q * 4]) = make_float4(0.f, 0.f, 0.f, 0.f);
            if (lane == 0) dl[lr] = 0.0f;
        }
    }
    __syncthreads();

    const int j4 = tid & 15;
    const int rp = tid >> 4;
    const int col0 = j4 * 4;
    float acc[2][4] = {};
    #pragma unroll 16
    for (int k = 0; k < 64; ++k) {
        const float4 wv = *reinterpret_cast<const float4*>(&W[(size_t)k * 64 + col0]);
        const float x0 = xs[rp * 2 + 0][k];
        const float x1 = xs[rp * 2 + 1][k];
        acc[0][0] = fmaf(x0, wv.x, acc[0][0]);
        acc[0][1] = fmaf(x0, wv.y, acc[0][1]);
        acc[0][2] = fmaf(x0, wv.z, acc[0][2]);
        acc[0][3] = fmaf(x0, wv.w, acc[0][3]);
        acc[1][0] = fmaf(x1, wv.x, acc[1][0]);
        acc[1][1] = fmaf(x1, wv.y, acc[1][1]);
        acc[1][2] = fmaf(x1, wv.z, acc[1][2]);
        acc[1][3] = fmaf(x1, wv.w, acc[1][3]);
    }
    #pragma unroll
    for (int r = 0; r < 2; ++r) {
        int row = row0 + rp * 2 + r;
        if (row < n) {
            float s = dl[rp * 2 + r];
            *reinterpret_cast<float4*>(&Y[(size_t)row * 64 + col0]) =
                make_float4(acc[r][0] * s, acc[r][1] * s, acc[r][2] * s, acc[r][3] * s);
        }
    }
}

// ---- fused agg + FFN head ----
__global__ __launch_bounds__(256) void agg_ffn_kernel(const float* __restrict__ A,
        const int* __restrict__ rowptr, const int* __restrict__ col,
        const float* __restrict__ dis, const float* __restrict__ bagg,
        const float* __restrict__ Wf1, const float* __restrict__ bf1,
        const float* __restrict__ Wf2, const float* __restrict__ bf2,
        float* __restrict__ out, int n) {
    __shared__ float xs[32][68];
    __shared__ float h1[32][65];
    const int tid = threadIdx.x;
    const int w = tid >> 6, lane = tid & 63;
    const int es = lane >> 4, q = lane & 15;
    const int row0 = blockIdx.x * 32;
    const float4 bv4 = *reinterpret_cast<const float4*>(&bagg[q * 4]);

    #pragma unroll
    for (int rr = 0; rr < 8; ++rr) {
        int lr = w * 8 + rr;
        int d = row0 + lr;
        if (d < n) {
            float4 acc = agg_row_vec(A, rowptr, col, d, es, q);
            float dd = dis[d];
            if (lane < 16) {
                float4 o;
                o.x = fmaxf(dd * acc.x + bv4.x, 0.0f);
                o.y = fmaxf(dd * acc.y + bv4.y, 0.0f);
                o.z = fmaxf(dd * acc.z + bv4.z, 0.0f);
                o.w = fmaxf(dd * acc.w + bv4.w, 0.0f);
                *reinterpret_cast<float4*>(&xs[lr][q * 4]) = o;
            }
        } else {
            if (lane < 16)
                *reinterpret_cast<float4*>(&xs[lr][q * 4]) = make_float4(0.f, 0.f, 0.f, 0.f);
        }
    }
    __syncthreads();

    // stage 1: h1 = relu(xs @ Wf1 + bf1)
    const int j4 = tid & 15;
    const int rp = tid >> 4;
    const int col0 = j4 * 4;
    float acc[2][4] = {};
    #pragma unroll 16
    for (int k = 0; k < 64; ++k) {
        const float4 wv = *reinterpret_cast<const float4*>(&Wf1[(size_t)k * 64 + col0]);
        const float x0 = xs[rp * 2 + 0][k];
        const float x1 = xs[rp * 2 + 1][k];
        acc[0][0] = fmaf(x0, wv.x, acc[0][0]);
        acc[0][1] = fmaf(x0, wv.y, acc[0][1]);
        acc[0][2] = fmaf(x0, wv.z, acc[0][2]);
        acc[0][3] = fmaf(x0, wv.w, acc[0][3]);
        acc[1][0] = fmaf(x1, wv.x, acc[1][0]);
        acc[1][1] = fmaf(x1, wv.y, acc[1][1]);
        acc[1][2] = fmaf(x1, wv.z, acc[1][2]);
        acc[1][3] = fmaf(x1, wv.w, acc[1][3]);
    }
    #pragma unroll
    for (int c = 0; c < 4; ++c) {
        float b = bf1[col0 + c];
        h1[rp * 2 + 0][col0 + c] = fmaxf(acc[0][c] + b, 0.0f);
        h1[rp * 2 + 1][col0 + c] = fmaxf(acc[1][c] + b, 0.0f);
    }
    __syncthreads();

    // stage 2: out[row, 0..9] = h1[row,:] @ Wf2 + bf2 ; 8 threads/row, 5 of 8 active
    const int lr = tid >> 3;
    const int cg = tid & 7;
    if (cg < 5) {
        float a0 = bf2[cg * 2 + 0], a1 = bf2[cg * 2 + 1];
        #pragma unroll 16
        for (int k = 0; k < 64; ++k) {
            float xv = h1[lr][k];
            a0 = fmaf(xv, Wf2[(size_t)k * 10 + cg * 2 + 0], a0);
            a1 = fmaf(xv, Wf2[(size_t)k * 10 + cg * 2 + 1], a1);
        }
        int row = row0 + lr;
        if (row < n) {
            out[(size_t)row * 10 + cg * 2 + 0] = a0;
            out[(size_t)row * 10 + cg * 2 + 1] = a1;
        }
    }
}

extern "C" void kernel_launch(void* const* d_in, const int* in_sizes, int n_in,
                              void* d_out, int out_size, void* d_ws, size_t ws_size,
                              hipStream_t stream) {
    const float* x   = (const float*)d_in[0];
    const int*   ei  = (const int*)d_in[1];
    const float* W1  = (const float*)d_in[2];
    const float* b1  = (const float*)d_in[3];
    const float* W2  = (const float*)d_in[4];
    const float* b2  = (const float*)d_in[5];
    const float* W3  = (const float*)d_in[6];
    const float* b3  = (const float*)d_in[7];
    const float* Wf1 = (const float*)d_in[8];
    const float* bf1 = (const float*)d_in[9];
    const float* Wf2 = (const float*)d_in[10];
    const float* bf2 = (const float*)d_in[11];
    float* out = (float*)d_out;

    const int N = N_NODES;
    const int E = in_sizes[1] / 2;
    const int* src = ei;
    const int* dst = ei + E;

    // workspace layout (all 4-byte elements)
    char* p = (char*)d_ws;
    int*   cnt    = (int*)p;                 p += (size_t)50176 * 4;
    float* dis    = (float*)p;               p += (size_t)50176 * 4;
    int*   rowptr = (int*)p;                 p += (size_t)(50176 + 64) * 4;
    int*   cursor = (int*)p;                 p += (size_t)50176 * 4;
    int*   bsum   = (int*)p;                 p += (size_t)256 * 4;
    int*   bbase  = (int*)p;                 p += (size_t)256 * 4;
    int*   col    = (int*)p;                 p += (size_t)E * 4;
    float* A1     = (float*)p;               p += (size_t)N * 64 * 4;
    float* A2     = (float*)p;

    // ---- CSR build + norms ----
    hipMemsetAsync(cnt, 0, (size_t)N * sizeof(int), stream);
    cnt_kernel<<<(E + 255) / 256, 256, 0, stream>>>(dst, E, cnt);
    bsum_kernel<<<NBLK, SCAN_BLK, 0, stream>>>(cnt, bsum, N);
    bscan_kernel<<<1, SCAN_BLK, 0, stream>>>(bsum, bbase, NBLK);
    scatter_scan_kernel<<<NBLK, SCAN_BLK, 0, stream>>>(cnt, bbase, rowptr, cursor, dis, N);
    fill_kernel<<<(E + 255) / 256, 256, 0, stream>>>(src, dst, E, cursor, col);

    const int grid32 = (N + 31) / 32;      // 1563 blocks

    // A1 = dis * (x @ W1)
    mm_tiled<128><<<grid32, 256, 0, stream>>>(x, W1, dis, A1, N);
    // A2 = dis * (relu(dis*(agg(A1)+self)+b1) @ W2)
    agg_mm_kernel<<<grid32, 256, 0, stream>>>(A1, rowptr, col, dis, b1, W2, A2, N);
    // A1 = dis * (relu(dis*(agg(A2)+self)+b2) @ W3)
    agg_mm_kernel<<<grid32, 256, 0, stream>>>(A2, rowptr, col, dis, b2, W3, A1, N);
    // out = ffn(relu(dis*(agg(A1)+self)+b3))
    agg_ffn_kernel<<<grid32, 256, 0, stream>>>(A1, rowptr, col, dis, b3,
                                               Wf1, bf1, Wf2, bf2, out, N);
}